// Round 2
// baseline (1652.660 us; speedup 1.0000x reference)
//
#include <hip/hip_runtime.h>
#include <math.h>

#define B_ 16
#define CIN_ 3
#define HID_ 64
#define S_ 16384
#define MODES_ 16
#define HEADS_ 4
#define CH_ 16
#define ED_ 8
#define NPSP_ 500
#define NPFR_ 200
#define LAYERS_ 4

// gelu(v) with erf via 12-term odd Taylor in y=v/sqrt(2); abs err < 2e-14 for
// |y| <= 0.708 (|v| <= 1.0). Rare fallback to libm erf.  Precision budget:
// g error must stay << 3e-9 (f32 storage rounding of h), poly gives ~1e-14.
__device__ __forceinline__ double gelu_exact(double v) {
    double y = v * 0.70710678118654752440;
    double t = y * y;
    double p = -1.2290555301717926e-09;
    p = fma(p, t, 1.4807192815879218e-08);
    p = fma(p, t, -1.6365838718281893e-07);
    p = fma(p, t, 1.6462114365889246e-06);
    p = fma(p, t, -1.4925650358406251e-05);
    p = fma(p, t, 1.2055332981789664e-04);
    p = fma(p, t, -8.5483270234508528e-04);
    p = fma(p, t, 5.2239776254421878e-03);
    p = fma(p, t, -2.6866170645131252e-02);
    p = fma(p, t, 1.1283791670955126e-01);
    p = fma(p, t, -3.7612638903183752e-01);
    p = fma(p, t, 1.1283791670955126e+00);
    double er = y * p;
    if (t > 0.5000001) er = erf(y);   // |v| > 1: rare, whole-wave skipped mostly
    return 0.5 * v * (1.0 + er);
}

// ---------------------------------------------------------------------------
// Lift: h[b,d,s] = sum_c x[b,c,s]*W[c,d] + bias[d]   (store h as f32, sC f64)
// ---------------------------------------------------------------------------
__global__ __launch_bounds__(256) void k_lift(const float* __restrict__ x,
                                              const float* __restrict__ W,
                                              const float* __restrict__ bias,
                                              float* __restrict__ h,
                                              double* __restrict__ sC) {
    int b = blockIdx.y;
    int s = blockIdx.x * 256 + threadIdx.x;
    const float* xb = x + (size_t)b * CIN_ * S_ + s;
    double x0 = (double)xb[0];
    double x1 = (double)xb[S_];
    double x2 = (double)xb[2 * S_];
    float* hb = h + (size_t)b * HID_ * S_ + s;
    double acc = 0.0;
    for (int d = 0; d < HID_; ++d) {
        double v = x0 * (double)W[d];
        v = fma(x1, (double)W[HID_ + d], v);
        v = fma(x2, (double)W[2 * HID_ + d], v);
        v += (double)bias[d];
        hb[(size_t)d * S_] = (float)v;
        acc += v;   // channel sum from UNROUNDED values (hash-sensitive)
    }
    sC[(size_t)b * S_ + s] = acc;
}

// ---------------------------------------------------------------------------
// Spatial hash: wsum over replicate-padded window, idx, and sum of gathered
// embeddings (Eb) for the mean path.
// ---------------------------------------------------------------------------
__global__ __launch_bounds__(256) void k_hash(const double* __restrict__ sC,
                                              const float* __restrict__ emb_l,
                                              int* __restrict__ idx,
                                              double* __restrict__ Eb) {
    int b = blockIdx.y;
    int s0 = blockIdx.x * 256;
    int t = threadIdx.x;
    __shared__ double sl[260];
    for (int j = t; j < 260; j += 256) {
        int p = s0 - 2 + j;
        p = p < 0 ? 0 : (p > S_ - 1 ? S_ - 1 : p);
        sl[j] = sC[(size_t)b * S_ + p];
    }
    __syncthreads();
    double wsum = ((sl[t] + sl[t + 1]) + sl[t + 2]) + sl[t + 3];
    int ti = (int)(wsum * 31.0);
    int id = ti % NPSP_;
    if (id < 0) id += NPSP_;
    idx[(size_t)b * S_ + s0 + t] = id;

    const float* er = emb_l + id * ED_;
    double ev[8];
#pragma unroll
    for (int k = 0; k < 8; k++) ev[k] = (double)er[k];

    int lane = t & 63, wv = t >> 6;
    __shared__ double red[4][8];
#pragma unroll
    for (int k = 0; k < 8; k++) {
        double v = ev[k];
        for (int off = 32; off > 0; off >>= 1) v += __shfl_down(v, off, 64);
        if (lane == 0) red[wv][k] = v;
    }
    __syncthreads();
    if (t < 8) {
        double v = red[0][t] + red[1][t] + red[2][t] + red[3][t];
        atomicAdd(&Eb[b * ED_ + t], v);
    }
}

// ---------------------------------------------------------------------------
// 16-mode direct DFT, 4 channels per block (twiddle recurrence amortized 4x).
// grid (16, B), 256 threads, ~275 VGPR -> 1 block/CU exactly resident.
// ---------------------------------------------------------------------------
__global__ __launch_bounds__(256, 1) void k_dft(const float* __restrict__ h,
                                                double* __restrict__ Xr,
                                                double* __restrict__ Xi) {
    int b = blockIdx.y;
    int c0 = blockIdx.x * 4;
    int t = threadIdx.x;
    const float* hp = h + ((size_t)(b * HID_ + c0)) * S_;

    double accC[4][16], accS[4][15];
#pragma unroll
    for (int ch = 0; ch < 4; ch++) {
#pragma unroll
        for (int m = 0; m < 16; m++) accC[ch][m] = 0.0;
#pragma unroll
        for (int m = 0; m < 15; m++) accS[ch][m] = 0.0;
    }

    double cb = cospi((double)t / 8192.0);
    double sb = sinpi((double)t / 8192.0);
    const double CD = 0.99518472667219688624;  // cos(pi/32)
    const double SD = 0.09801714032956060199;  // sin(pi/32)

    for (int k = 0; k < 64; k++) {
        int s = t + (k << 8);
        double hv[4];
#pragma unroll
        for (int ch = 0; ch < 4; ch++) hv[ch] = (double)hp[(size_t)ch * S_ + s];
#pragma unroll
        for (int ch = 0; ch < 4; ch++) accC[ch][0] += hv[ch];
        double c = cb, sv = sb;
#pragma unroll
        for (int m = 1; m < 16; m++) {
#pragma unroll
            for (int ch = 0; ch < 4; ch++) {
                accC[ch][m] = fma(hv[ch], c, accC[ch][m]);
                accS[ch][m - 1] = fma(hv[ch], sv, accS[ch][m - 1]);
            }
            double cn = c * cb - sv * sb;
            double sn = sv * cb + c * sb;
            c = cn; sv = sn;
        }
        double c2 = cb * CD - sb * SD;
        double s2 = sb * CD + cb * SD;
        cb = c2; sb = s2;
    }

    int lane = t & 63, wv = t >> 6;
    __shared__ double red[4][4][32];
#pragma unroll
    for (int ch = 0; ch < 4; ch++) {
#pragma unroll
        for (int m = 0; m < 16; m++) {
            double v = accC[ch][m];
            for (int off = 32; off > 0; off >>= 1) v += __shfl_down(v, off, 64);
            if (lane == 0) red[wv][ch][m] = v;
        }
#pragma unroll
        for (int m = 0; m < 15; m++) {
            double v = accS[ch][m];
            for (int off = 32; off > 0; off >>= 1) v += __shfl_down(v, off, 64);
            if (lane == 0) red[wv][ch][16 + m] = v;
        }
    }
    __syncthreads();
    if (t < 128) {
        int ch = t >> 5, j = t & 31;
        int c = c0 + ch;
        if (j < 16) {
            double v = red[0][ch][j] + red[1][ch][j] + red[2][ch][j] + red[3][ch][j];
            Xr[((size_t)b * HID_ + c) * MODES_ + j] = v;
        } else if (j < 31) {
            int m = j - 15;
            double v = red[0][ch][j] + red[1][ch][j] + red[2][ch][j] + red[3][ch][j];
            Xi[((size_t)b * HID_ + c) * MODES_ + m] = -v;
        } else {
            Xi[((size_t)b * HID_ + c) * MODES_ + 0] = 0.0;  // DC imag = 0
        }
    }
}

// ---------------------------------------------------------------------------
// Per-batch small stage: mag/fidx, MX complex mixing, P, means, gating MLP,
// softmax -> FUSED reconstruction coefficients:
//   AB[c][m] = { k_m*(w1*MXr + w2*P),  m==0 ? 0 : -k_m*w1*MXi },  k_m=(m?2:1)/S
//   Wb[b][0..511]  = w0 * sp_W,   Wb[b][512..575] = w0 * sp_b
// ---------------------------------------------------------------------------
__global__ __launch_bounds__(256) void k_small(const double* __restrict__ Xr,
                                               const double* __restrict__ Xi,
                                               const float* __restrict__ mWr,
                                               const float* __restrict__ mWi,
                                               const float* __restrict__ fr_emb_l,
                                               const float* __restrict__ fr_W_l,
                                               const float* __restrict__ fr_b_l,
                                               const double* __restrict__ Eb,
                                               const float* __restrict__ sp_W_l,
                                               const float* __restrict__ sp_b_l,
                                               const float* __restrict__ gW1,
                                               const float* __restrict__ gb1,
                                               const float* __restrict__ gW2,
                                               const float* __restrict__ gb2,
                                               double2* __restrict__ ABg,
                                               double* __restrict__ Wbg) {
    int b = blockIdx.x;
    int t = threadIdx.x;
    __shared__ double sXr[HID_ * MODES_], sXi[HID_ * MODES_];
    __shared__ double sMr[HID_ * MODES_], sMi[HID_ * MODES_], sP[HID_ * MODES_];
    __shared__ double gg[192], h1s[64], sww[3];
    __shared__ int magI[MODES_];
    __shared__ int fidxS;

    for (int j = t; j < HID_ * MODES_; j += 256) {
        sXr[j] = Xr[(size_t)b * HID_ * MODES_ + j];
        sXi[j] = Xi[(size_t)b * HID_ * MODES_ + j];
    }
    __syncthreads();

    if (t < MODES_) {
        double acc = 0.0;
        for (int c = 0; c < HID_; c++) {
            double re = sXr[c * MODES_ + t], im = sXi[c * MODES_ + t];
            acc += sqrt(re * re + im * im);
        }
        magI[t] = (int)(acc * (1.0 / 64.0) * 1000.0);
    }

    for (int u = t; u < HID_ * MODES_; u += 256) {
        int hh = u >> 8, rem = u & 255, o = rem >> 4, m = rem & 15;
        double aR = 0.0, aI = 0.0;
        for (int i = 0; i < CH_; i++) {
            int ci = hh * CH_ + i;
            double xr = sXr[ci * MODES_ + m];
            double xi = sXi[ci * MODES_ + m];
            double wr = (double)mWr[((size_t)(hh * CH_ + i) * CH_ + o) * MODES_ + m];
            double wi = (double)mWi[((size_t)(hh * CH_ + i) * CH_ + o) * MODES_ + m];
            aR += xr * wr - xi * wi;
            aI += xr * wi + xi * wr;
        }
        int co = hh * CH_ + o;
        sMr[co * MODES_ + m] = aR;
        sMi[co * MODES_ + m] = aI;
    }
    __syncthreads();

    if (t == 0) {
        int ssum = 0;
        for (int m = 0; m < MODES_; m++) ssum += magI[m];
        int f = ssum % NPFR_;
        if (f < 0) f += NPFR_;
        fidxS = f;
    }
    __syncthreads();

    {
        const float* fe = fr_emb_l + fidxS * ED_;
        for (int u = t; u < HID_ * MODES_; u += 256) {
            double acc = 0.0;
            for (int e = 0; e < ED_; e++)
                acc += (double)fe[e] * (double)fr_W_l[e * (HID_ * MODES_) + u];
            sP[u] = acc + (double)fr_b_l[u];
        }
    }
    __syncthreads();

    if (t < 64) {
        double a = 0.0;
        for (int e = 0; e < ED_; e++)
            a += Eb[b * ED_ + e] * (double)sp_W_l[e * 64 + t];
        gg[t]       = a * (1.0 / 16384.0) + (double)sp_b_l[t];
        gg[64 + t]  = sMr[t * MODES_ + 0] * (1.0 / 16384.0);
        gg[128 + t] = sP[t * MODES_ + 0] * (1.0 / 16384.0);
    }
    __syncthreads();
    if (t < 64) {
        double a = 0.0;
        for (int k = 0; k < 192; k++) a += gg[k] * (double)gW1[k * 64 + t];
        a += (double)gb1[t];
        h1s[t] = a > 0.0 ? a : 0.0;
    }
    __syncthreads();
    if (t == 0) {
        double l[3];
        for (int j = 0; j < 3; j++) {
            double a = 0.0;
            for (int k = 0; k < 64; k++) a += h1s[k] * (double)gW2[k * 3 + j];
            l[j] = a + (double)gb2[j];
        }
        double mx = fmax(l[0], fmax(l[1], l[2]));
        double e0 = exp(l[0] - mx), e1 = exp(l[1] - mx), e2 = exp(l[2] - mx);
        double sum = e0 + e1 + e2;
        sww[0] = e0 / sum; sww[1] = e1 / sum; sww[2] = e2 / sum;
    }
    __syncthreads();

    double w0s = sww[0], w1s = sww[1], w2s = sww[2];
    for (int u = t; u < HID_ * MODES_; u += 256) {
        int m = u & 15;
        double km = (m == 0 ? 1.0 : 2.0) * (1.0 / 16384.0);
        double2 o;
        o.x = km * (w1s * sMr[u] + w2s * sP[u]);
        o.y = (m == 0) ? 0.0 : -(km * w1s * sMi[u]);
        ABg[(size_t)b * 1024 + u] = o;
    }
    for (int u = t; u < 512; u += 256) Wbg[(size_t)b * 576 + u] = w0s * (double)sp_W_l[u];
    if (t < 64) Wbg[(size_t)b * 576 + 512 + t] = w0s * (double)sp_b_l[t];
}

// ---------------------------------------------------------------------------
// Reconstruction: 2 positions per thread (block covers 512 s), all 64 channels.
// v = Wb_bias[c] + sum_e e[e]*Wb[e,c] + sum_m (AB.x*cm + AB.y*sm); gelu; store.
// Second position's basis derived from the first via constant pi*m/32 rotation.
// ---------------------------------------------------------------------------
__global__ __launch_bounds__(256, 2) void k_recon(const int* __restrict__ idx,
                                                  const float* __restrict__ sp_emb_l,
                                                  const double2* __restrict__ ABg,
                                                  const double* __restrict__ Wbg,
                                                  float* __restrict__ h,
                                                  double* __restrict__ sC) {
    int b = blockIdx.y;
    int s0 = blockIdx.x * 512;
    int t = threadIdx.x;
    __shared__ double2 sAB[HID_ * MODES_];   // 16 KB
    __shared__ double sW[576];               // 4.5 KB

    for (int j = t; j < HID_ * MODES_; j += 256) sAB[j] = ABg[(size_t)b * 1024 + j];
    for (int j = t; j < 576; j += 256) sW[j] = Wbg[(size_t)b * 576 + j];
    __syncthreads();

    int s1 = s0 + t, s2 = s1 + 256;
    int id1 = idx[(size_t)b * S_ + s1];
    int id2 = idx[(size_t)b * S_ + s2];
    const float4* ev = reinterpret_cast<const float4*>(sp_emb_l);
    float4 a0 = ev[2 * id1], a1 = ev[2 * id1 + 1];
    float4 b0 = ev[2 * id2], b1 = ev[2 * id2 + 1];
    double e1[8] = {a0.x, a0.y, a0.z, a0.w, a1.x, a1.y, a1.z, a1.w};
    double e2[8] = {b0.x, b0.y, b0.z, b0.w, b1.x, b1.y, b1.z, b1.w};

    const double KC[16] = {1.0, 0.99518472667219688624, 0.98078528040323044913,
        0.95694033573220886494, 0.92387953251128675613, 0.88192126434835502971,
        0.83146961230254523708, 0.77301045336273696081, 0.70710678118654752440,
        0.63439328416364549822, 0.55557023301960222474, 0.47139673682599764856,
        0.38268343236508977173, 0.29028467725446236764, 0.19509032201612826785,
        0.09801714032956060199};
    const double KS[16] = {0.0, 0.09801714032956060199, 0.19509032201612826785,
        0.29028467725446236764, 0.38268343236508977173, 0.47139673682599764856,
        0.55557023301960222474, 0.63439328416364549822, 0.70710678118654752440,
        0.77301045336273696081, 0.83146961230254523708, 0.88192126434835502971,
        0.92387953251128675613, 0.95694033573220886494, 0.98078528040323044913,
        0.99518472667219688624};

    double cb = cospi((double)s1 / 8192.0);
    double sb = sinpi((double)s1 / 8192.0);
    double cm1[16], sm1[16], cm2[16], sm2[16];
    cm1[0] = 1.0; sm1[0] = 0.0;
    cm1[1] = cb;  sm1[1] = sb;
#pragma unroll
    for (int m = 2; m < 16; m++) {
        cm1[m] = cm1[m - 1] * cb - sm1[m - 1] * sb;
        sm1[m] = sm1[m - 1] * cb + cm1[m - 1] * sb;
    }
#pragma unroll
    for (int m = 0; m < 16; m++) {
        cm2[m] = cm1[m] * KC[m] - sm1[m] * KS[m];
        sm2[m] = sm1[m] * KC[m] + cm1[m] * KS[m];
    }

    float* hb = h + (size_t)b * HID_ * S_;
    double cs1 = 0.0, cs2 = 0.0;
    for (int c = 0; c < HID_; c++) {
        double v1 = sW[512 + c], v2 = v1;
#pragma unroll
        for (int k = 0; k < 8; k++) {
            double w = sW[k * 64 + c];
            v1 = fma(e1[k], w, v1);
            v2 = fma(e2[k], w, v2);
        }
#pragma unroll
        for (int m = 0; m < 16; m++) {
            double2 ab = sAB[c * 16 + m];
            v1 = fma(ab.x, cm1[m], v1);
            v1 = fma(ab.y, sm1[m], v1);
            v2 = fma(ab.x, cm2[m], v2);
            v2 = fma(ab.y, sm2[m], v2);
        }
        double g1 = gelu_exact(v1);
        double g2 = gelu_exact(v2);
        hb[(size_t)c * S_ + s1] = (float)g1;
        hb[(size_t)c * S_ + s2] = (float)g2;
        cs1 += g1; cs2 += g2;
    }
    sC[(size_t)b * S_ + s1] = cs1;
    sC[(size_t)b * S_ + s2] = cs2;
}

// ---------------------------------------------------------------------------
// Projection: out[b,s] = sum_d h[b,d,s]*pW[d] + pb
// ---------------------------------------------------------------------------
__global__ __launch_bounds__(256) void k_proj(const float* __restrict__ h,
                                              const float* __restrict__ pW,
                                              const float* __restrict__ pb,
                                              float* __restrict__ out) {
    int b = blockIdx.y;
    int s = blockIdx.x * 256 + threadIdx.x;
    const float* hb = h + (size_t)b * HID_ * S_ + s;
    double acc = 0.0;
    for (int d = 0; d < HID_; d++)
        acc += (double)hb[(size_t)d * S_] * (double)pW[d];
    out[(size_t)b * S_ + s] = (float)(acc + (double)pb[0]);
}

extern "C" void kernel_launch(void* const* d_in, const int* in_sizes, int n_in,
                              void* d_out, int out_size, void* d_ws, size_t ws_size,
                              hipStream_t stream) {
    const float* x      = (const float*)d_in[0];
    const float* lift_W = (const float*)d_in[1];
    const float* lift_b = (const float*)d_in[2];
    const float* proj_W = (const float*)d_in[3];
    const float* proj_b = (const float*)d_in[4];
    const float* sp_emb = (const float*)d_in[5];
    const float* sp_W   = (const float*)d_in[6];
    const float* sp_b   = (const float*)d_in[7];
    const float* fr_emb = (const float*)d_in[8];
    const float* fr_W   = (const float*)d_in[9];
    const float* fr_b   = (const float*)d_in[10];
    const float* g_W1   = (const float*)d_in[11];
    const float* g_b1   = (const float*)d_in[12];
    const float* g_W2   = (const float*)d_in[13];
    const float* g_b2   = (const float*)d_in[14];
    const float* mhf_Wr = (const float*)d_in[15];
    const float* mhf_Wi = (const float*)d_in[16];

    char* ws = (char*)d_ws;
    float* h    = (float*)ws;   ws += (size_t)B_ * HID_ * S_ * 4;          // 64 MiB
    double* sC  = (double*)ws;  ws += (size_t)B_ * S_ * 8;                 // 2 MiB
    int* idx    = (int*)ws;     ws += (size_t)B_ * S_ * 4;                 // 1 MiB
    double* Xr  = (double*)ws;  ws += (size_t)B_ * HID_ * MODES_ * 8;
    double* Xi  = (double*)ws;  ws += (size_t)B_ * HID_ * MODES_ * 8;
    double2* AB = (double2*)ws; ws += (size_t)B_ * HID_ * MODES_ * 16;
    double* Wb  = (double*)ws;  ws += (size_t)B_ * 576 * 8;
    double* Eb  = (double*)ws;  ws += (size_t)LAYERS_ * B_ * ED_ * 8;

    hipMemsetAsync(Eb, 0, (size_t)LAYERS_ * B_ * ED_ * 8, stream);

    dim3 blk(256);
    k_lift<<<dim3(S_ / 256, B_), blk, 0, stream>>>(x, lift_W, lift_b, h, sC);

    for (int lay = 0; lay < LAYERS_; ++lay) {
        k_hash<<<dim3(S_ / 256, B_), blk, 0, stream>>>(
            sC, sp_emb + (size_t)lay * NPSP_ * ED_, idx, Eb + (size_t)lay * B_ * ED_);
        k_dft<<<dim3(HID_ / 4, B_), blk, 0, stream>>>(h, Xr, Xi);
        k_small<<<dim3(B_), blk, 0, stream>>>(
            Xr, Xi,
            mhf_Wr + (size_t)lay * HEADS_ * CH_ * CH_ * MODES_,
            mhf_Wi + (size_t)lay * HEADS_ * CH_ * CH_ * MODES_,
            fr_emb + (size_t)lay * NPFR_ * ED_,
            fr_W + (size_t)lay * ED_ * HID_ * MODES_,
            fr_b + (size_t)lay * HID_ * MODES_,
            Eb + (size_t)lay * B_ * ED_,
            sp_W + (size_t)lay * ED_ * HID_,
            sp_b + (size_t)lay * HID_,
            g_W1 + (size_t)lay * 192 * 64,
            g_b1 + (size_t)lay * 64,
            g_W2 + (size_t)lay * 64 * 3,
            g_b2 + (size_t)lay * 3,
            AB, Wb);
        k_recon<<<dim3(S_ / 512, B_), blk, 0, stream>>>(
            idx, sp_emb + (size_t)lay * NPSP_ * ED_, AB, Wb, h, sC);
    }

    k_proj<<<dim3(S_ / 256, B_), blk, 0, stream>>>(h, proj_W, proj_b, (float*)d_out);
}

// Round 3
// 1107.393 us; speedup vs baseline: 1.4924x; 1.4924x over previous
//
#include <hip/hip_runtime.h>
#include <math.h>

#define B_ 16
#define CIN_ 3
#define HID_ 64
#define S_ 16384
#define MODES_ 16
#define HEADS_ 4
#define CH_ 16
#define ED_ 8
#define NPSP_ 500
#define NPFR_ 200
#define LAYERS_ 4

// gelu(v) with erf via 12-term odd Taylor in y=v/sqrt(2); abs err < 2e-14 for
// |v| <= 1.0; rare libm fallback. Error budget: h is stored f32 (3e-9
// rounding), poly adds ~1e-14 — negligible vs both prior passing rounds.
__device__ __forceinline__ double gelu_exact(double v) {
    double y = v * 0.70710678118654752440;
    double t = y * y;
    double p = -1.2290555301717926e-09;
    p = fma(p, t, 1.4807192815879218e-08);
    p = fma(p, t, -1.6365838718281893e-07);
    p = fma(p, t, 1.6462114365889246e-06);
    p = fma(p, t, -1.4925650358406251e-05);
    p = fma(p, t, 1.2055332981789664e-04);
    p = fma(p, t, -8.5483270234508528e-04);
    p = fma(p, t, 5.2239776254421878e-03);
    p = fma(p, t, -2.6866170645131252e-02);
    p = fma(p, t, 1.1283791670955126e-01);
    p = fma(p, t, -3.7612638903183752e-01);
    p = fma(p, t, 1.1283791670955126e+00);
    double er = y * p;
    if (t > 0.5000001) er = erf(y);
    return 0.5 * v * (1.0 + er);
}

// ---------------------------------------------------------------------------
// Lift: h[b,d,s] = sum_c x[b,c,s]*W[c,d] + bias[d]   (store h as f32, sC f64)
// ---------------------------------------------------------------------------
__global__ __launch_bounds__(256) void k_lift(const float* __restrict__ x,
                                              const float* __restrict__ W,
                                              const float* __restrict__ bias,
                                              float* __restrict__ h,
                                              double* __restrict__ sC) {
    int b = blockIdx.y;
    int s = blockIdx.x * 256 + threadIdx.x;
    const float* xb = x + (size_t)b * CIN_ * S_ + s;
    double x0 = (double)xb[0];
    double x1 = (double)xb[S_];
    double x2 = (double)xb[2 * S_];
    float* hb = h + (size_t)b * HID_ * S_ + s;
    double acc = 0.0;
    for (int d = 0; d < HID_; ++d) {
        double v = x0 * (double)W[d];
        v = fma(x1, (double)W[HID_ + d], v);
        v = fma(x2, (double)W[2 * HID_ + d], v);
        v += (double)bias[d];
        hb[(size_t)d * S_] = (float)v;
        acc += v;   // channel sum from UNROUNDED values (hash-sensitive)
    }
    sC[(size_t)b * S_ + s] = acc;
}

// ---------------------------------------------------------------------------
// Spatial hash: wsum (replicate-padded window), idx, and block-reduced sum of
// gathered embeddings (Eb) for the mean path.
// ---------------------------------------------------------------------------
__global__ __launch_bounds__(256) void k_hash(const double* __restrict__ sC,
                                              const float* __restrict__ emb_l,
                                              int* __restrict__ idx,
                                              double* __restrict__ Eb) {
    int b = blockIdx.y;
    int s0 = blockIdx.x * 256;
    int t = threadIdx.x;
    __shared__ double sl[260];
    for (int j = t; j < 260; j += 256) {
        int p = s0 - 2 + j;
        p = p < 0 ? 0 : (p > S_ - 1 ? S_ - 1 : p);
        sl[j] = sC[(size_t)b * S_ + p];
    }
    __syncthreads();
    double wsum = ((sl[t] + sl[t + 1]) + sl[t + 2]) + sl[t + 3];
    int ti = (int)(wsum * 31.0);
    int id = ti % NPSP_;
    if (id < 0) id += NPSP_;
    idx[(size_t)b * S_ + s0 + t] = id;

    const float* er = emb_l + id * ED_;
    double ev[8];
#pragma unroll
    for (int k = 0; k < 8; k++) ev[k] = (double)er[k];

    int lane = t & 63, wv = t >> 6;
    __shared__ double red[4][8];
#pragma unroll
    for (int k = 0; k < 8; k++) {
        double v = ev[k];
        for (int off = 32; off > 0; off >>= 1) v += __shfl_down(v, off, 64);
        if (lane == 0) red[wv][k] = v;
    }
    __syncthreads();
    if (t < 8) {
        double v = red[0][t] + red[1][t] + red[2][t] + red[3][t];
        atomicAdd(&Eb[b * ED_ + t], v);
    }
}

// ---------------------------------------------------------------------------
// 16-mode direct DFT, 2 channels per block (round-1 proven shape: 96..165
// VGPR, no spills).
// ---------------------------------------------------------------------------
__global__ __launch_bounds__(256) void k_dft(const float* __restrict__ h,
                                             double* __restrict__ Xr,
                                             double* __restrict__ Xi) {
    int b = blockIdx.y;
    int c0 = blockIdx.x * 2;
    int t = threadIdx.x;
    const float* h0 = h + ((size_t)(b * HID_ + c0)) * S_;
    const float* h1 = h0 + S_;

    double acc[64];
#pragma unroll
    for (int k = 0; k < 64; k++) acc[k] = 0.0;

    double cb = cospi((double)t / 8192.0);
    double sb = sinpi((double)t / 8192.0);
    const double CD = 0.99518472667219688624;  // cos(pi/32)
    const double SD = 0.09801714032956060199;  // sin(pi/32)

    for (int k = 0; k < 64; k++) {
        int s = t + (k << 8);
        double hv0 = (double)h0[s];
        double hv1 = (double)h1[s];
        acc[0] += hv0;
        acc[32] += hv1;
        double c = cb, sv = sb;
#pragma unroll
        for (int m = 1; m < 16; m++) {
            acc[m]      = fma(hv0, c,  acc[m]);
            acc[16 + m] = fma(hv0, sv, acc[16 + m]);
            acc[32 + m] = fma(hv1, c,  acc[32 + m]);
            acc[48 + m] = fma(hv1, sv, acc[48 + m]);
            double cn = c * cb - sv * sb;
            double sn = sv * cb + c * sb;
            c = cn; sv = sn;
        }
        double c2 = cb * CD - sb * SD;
        double s2 = sb * CD + cb * SD;
        cb = c2; sb = s2;
    }

    int lane = t & 63, wv = t >> 6;
    __shared__ double red[4][64];
#pragma unroll
    for (int k = 0; k < 64; k++) {
        double v = acc[k];
        for (int off = 32; off > 0; off >>= 1) v += __shfl_down(v, off, 64);
        if (lane == 0) red[wv][k] = v;
    }
    __syncthreads();
    if (t < 64) {
        double v = red[0][t] + red[1][t] + red[2][t] + red[3][t];
        int cc = t >> 5, im = (t >> 4) & 1, m = t & 15;
        int c = c0 + cc;
        if (im) Xi[((size_t)b * HID_ + c) * MODES_ + m] = -v;
        else    Xr[((size_t)b * HID_ + c) * MODES_ + m] = v;
    }
}

// ---------------------------------------------------------------------------
// MX complex head mixing, one block per (head, b): 64 blocks instead of
// burying this in the 16-block gate kernel. Thread t -> output (o = t>>4,
// m = t&15) of its head.
// ---------------------------------------------------------------------------
__global__ __launch_bounds__(256) void k_mx(const double* __restrict__ Xr,
                                            const double* __restrict__ Xi,
                                            const float* __restrict__ mWr,
                                            const float* __restrict__ mWi,
                                            double* __restrict__ MXr,
                                            double* __restrict__ MXi) {
    int hh = blockIdx.x, b = blockIdx.y, t = threadIdx.x;
    int o = t >> 4, m = t & 15;
    const double* xr = Xr + ((size_t)b * HID_ + hh * CH_) * MODES_;
    const double* xi = Xi + ((size_t)b * HID_ + hh * CH_) * MODES_;
    const float* wr = mWr + (size_t)hh * CH_ * CH_ * MODES_;
    const float* wi = mWi + (size_t)hh * CH_ * CH_ * MODES_;
    double aR = 0.0, aI = 0.0;
#pragma unroll 4
    for (int i = 0; i < CH_; i++) {
        double xrv = xr[i * MODES_ + m];
        double xiv = xi[i * MODES_ + m];
        double wrv = (double)wr[(i * CH_ + o) * MODES_ + m];
        double wiv = (double)wi[(i * CH_ + o) * MODES_ + m];
        aR += xrv * wrv - xiv * wiv;
        aI += xrv * wiv + xiv * wrv;
    }
    int co = hh * CH_ + o;
    MXr[(size_t)b * 1024 + co * MODES_ + m] = aR;
    MXi[(size_t)b * 1024 + co * MODES_ + m] = aI;
}

// ---------------------------------------------------------------------------
// Gate/pack (slim, 16 blocks): mag/fidx, P, means, gating MLP, softmax ->
//   AB[c][m] = { k_m*(w1*MXr + w2*P),  m==0 ? 0 : -k_m*w1*MXi }, k_m=(m?2:1)/S
//   Wb[0..511] = w0*sp_W, Wb[512..575] = w0*sp_b
// ---------------------------------------------------------------------------
__global__ __launch_bounds__(256) void k_gate(const double* __restrict__ Xr,
                                              const double* __restrict__ Xi,
                                              const double* __restrict__ MXr,
                                              const double* __restrict__ MXi,
                                              const float* __restrict__ fr_emb_l,
                                              const float* __restrict__ fr_W_l,
                                              const float* __restrict__ fr_b_l,
                                              const double* __restrict__ Eb,
                                              const float* __restrict__ sp_W_l,
                                              const float* __restrict__ sp_b_l,
                                              const float* __restrict__ gW1,
                                              const float* __restrict__ gb1,
                                              const float* __restrict__ gW2,
                                              const float* __restrict__ gb2,
                                              double2* __restrict__ ABg,
                                              double* __restrict__ Wbg) {
    int b = blockIdx.x;
    int t = threadIdx.x;
    __shared__ double sP[HID_ * MODES_];
    __shared__ double gg[192], h1s[64], sww[3];
    __shared__ int magI[MODES_];
    __shared__ int fidxS;

    if (t < MODES_) {
        double acc = 0.0;
        for (int c = 0; c < HID_; c++) {
            double re = Xr[(size_t)b * 1024 + c * MODES_ + t];
            double im = Xi[(size_t)b * 1024 + c * MODES_ + t];
            acc += sqrt(re * re + im * im);
        }
        magI[t] = (int)(acc * (1.0 / 64.0) * 1000.0);
    }
    __syncthreads();
    if (t == 0) {
        int ssum = 0;
        for (int m = 0; m < MODES_; m++) ssum += magI[m];
        int f = ssum % NPFR_;
        if (f < 0) f += NPFR_;
        fidxS = f;
    }
    __syncthreads();

    {
        const float* fe = fr_emb_l + fidxS * ED_;
        for (int u = t; u < HID_ * MODES_; u += 256) {
            double acc = 0.0;
            for (int e = 0; e < ED_; e++)
                acc += (double)fe[e] * (double)fr_W_l[e * (HID_ * MODES_) + u];
            sP[u] = acc + (double)fr_b_l[u];
        }
    }
    __syncthreads();

    if (t < 64) {
        double a = 0.0;
        for (int e = 0; e < ED_; e++)
            a += Eb[b * ED_ + e] * (double)sp_W_l[e * 64 + t];
        gg[t]       = a * (1.0 / 16384.0) + (double)sp_b_l[t];
        gg[64 + t]  = MXr[(size_t)b * 1024 + t * MODES_] * (1.0 / 16384.0);
        gg[128 + t] = sP[t * MODES_] * (1.0 / 16384.0);
    }
    __syncthreads();
    if (t < 64) {
        double a = 0.0;
        for (int k = 0; k < 192; k++) a += gg[k] * (double)gW1[k * 64 + t];
        a += (double)gb1[t];
        h1s[t] = a > 0.0 ? a : 0.0;
    }
    __syncthreads();
    if (t == 0) {
        double l[3];
        for (int j = 0; j < 3; j++) {
            double a = 0.0;
            for (int k = 0; k < 64; k++) a += h1s[k] * (double)gW2[k * 3 + j];
            l[j] = a + (double)gb2[j];
        }
        double mx = fmax(l[0], fmax(l[1], l[2]));
        double e0 = exp(l[0] - mx), e1 = exp(l[1] - mx), e2 = exp(l[2] - mx);
        double sum = e0 + e1 + e2;
        sww[0] = e0 / sum; sww[1] = e1 / sum; sww[2] = e2 / sum;
    }
    __syncthreads();

    double w0s = sww[0], w1s = sww[1], w2s = sww[2];
    for (int u = t; u < HID_ * MODES_; u += 256) {
        int m = u & 15;
        double km = (m == 0 ? 1.0 : 2.0) * (1.0 / 16384.0);
        double2 o;
        o.x = km * (w1s * MXr[(size_t)b * 1024 + u] + w2s * sP[u]);
        o.y = (m == 0) ? 0.0 : -(km * w1s * MXi[(size_t)b * 1024 + u]);
        ABg[(size_t)b * 1024 + u] = o;
    }
    for (int u = t; u < 512; u += 256) Wbg[(size_t)b * 576 + u] = w0s * (double)sp_W_l[u];
    if (t < 64) Wbg[(size_t)b * 576 + 512 + t] = w0s * (double)sp_b_l[t];
}

// ---------------------------------------------------------------------------
// Reconstruction, round-1 register shape (1 position/thread, cm/sm = 64 VGPR)
// + AB fusion + poly gelu. AB/Wb are read with BLOCK-UNIFORM indices straight
// from global so the compiler lowers them to s_load (scalar pipe, overlaps
// the fp64 VALU); LDS holds only the divergent semb gather table.
// ---------------------------------------------------------------------------
__global__ __launch_bounds__(256) void k_recon(const int* __restrict__ idx,
                                               const float* __restrict__ sp_emb_l,
                                               const double2* __restrict__ ABg,
                                               const double* __restrict__ Wbg,
                                               float* __restrict__ h,
                                               double* __restrict__ sC) {
    int b = blockIdx.y;
    int s = blockIdx.x * 256 + threadIdx.x;
    int t = threadIdx.x;
    __shared__ float semb[NPSP_ * 9];   // stride 9: break 8-float bank stride
    for (int j = t; j < NPSP_ * 8; j += 256) {
        int r = j >> 3, e2 = j & 7;
        semb[r * 9 + e2] = sp_emb_l[j];
    }
    __syncthreads();

    int id = idx[(size_t)b * S_ + s];
    double e[8];
#pragma unroll
    for (int k = 0; k < 8; k++) e[k] = (double)semb[id * 9 + k];

    double cb = cospi((double)s / 8192.0);
    double sb = sinpi((double)s / 8192.0);
    double cm[16], sm[16];
    cm[0] = 1.0; sm[0] = 0.0;
    cm[1] = cb;  sm[1] = sb;
#pragma unroll
    for (int m = 2; m < 16; m++) {
        cm[m] = cm[m - 1] * cb - sm[m - 1] * sb;
        sm[m] = sm[m - 1] * cb + cm[m - 1] * sb;
    }

    const double2* ab = ABg + (size_t)b * 1024;     // block-uniform -> s_load
    const double* wb  = Wbg + (size_t)b * 576;      // block-uniform -> s_load
    float* hb = h + (size_t)b * HID_ * S_ + s;
    double csum = 0.0;
    for (int c = 0; c < HID_; c++) {
        double v = wb[512 + c];
#pragma unroll
        for (int k = 0; k < 8; k++) v = fma(e[k], wb[k * 64 + c], v);
#pragma unroll
        for (int m = 0; m < 16; m++) {
            double2 q = ab[c * 16 + m];
            v = fma(q.x, cm[m], v);
            v = fma(q.y, sm[m], v);
        }
        double g = gelu_exact(v);
        hb[(size_t)c * S_] = (float)g;
        csum += g;   // unrounded channel sum for the next layer's hash
    }
    sC[(size_t)b * S_ + s] = csum;
}

// ---------------------------------------------------------------------------
// Projection: out[b,s] = sum_d h[b,d,s]*pW[d] + pb
// ---------------------------------------------------------------------------
__global__ __launch_bounds__(256) void k_proj(const float* __restrict__ h,
                                              const float* __restrict__ pW,
                                              const float* __restrict__ pb,
                                              float* __restrict__ out) {
    int b = blockIdx.y;
    int s = blockIdx.x * 256 + threadIdx.x;
    const float* hb = h + (size_t)b * HID_ * S_ + s;
    double acc = 0.0;
    for (int d = 0; d < HID_; d++)
        acc += (double)hb[(size_t)d * S_] * (double)pW[d];
    out[(size_t)b * S_ + s] = (float)(acc + (double)pb[0]);
}

extern "C" void kernel_launch(void* const* d_in, const int* in_sizes, int n_in,
                              void* d_out, int out_size, void* d_ws, size_t ws_size,
                              hipStream_t stream) {
    const float* x      = (const float*)d_in[0];
    const float* lift_W = (const float*)d_in[1];
    const float* lift_b = (const float*)d_in[2];
    const float* proj_W = (const float*)d_in[3];
    const float* proj_b = (const float*)d_in[4];
    const float* sp_emb = (const float*)d_in[5];
    const float* sp_W   = (const float*)d_in[6];
    const float* sp_b   = (const float*)d_in[7];
    const float* fr_emb = (const float*)d_in[8];
    const float* fr_W   = (const float*)d_in[9];
    const float* fr_b   = (const float*)d_in[10];
    const float* g_W1   = (const float*)d_in[11];
    const float* g_b1   = (const float*)d_in[12];
    const float* g_W2   = (const float*)d_in[13];
    const float* g_b2   = (const float*)d_in[14];
    const float* mhf_Wr = (const float*)d_in[15];
    const float* mhf_Wi = (const float*)d_in[16];

    char* ws = (char*)d_ws;
    float* h    = (float*)ws;   ws += (size_t)B_ * HID_ * S_ * 4;          // 64 MiB
    double* sC  = (double*)ws;  ws += (size_t)B_ * S_ * 8;                 // 2 MiB
    int* idx    = (int*)ws;     ws += (size_t)B_ * S_ * 4;                 // 1 MiB
    double* Xr  = (double*)ws;  ws += (size_t)B_ * HID_ * MODES_ * 8;
    double* Xi  = (double*)ws;  ws += (size_t)B_ * HID_ * MODES_ * 8;
    double* MXr = (double*)ws;  ws += (size_t)B_ * HID_ * MODES_ * 8;
    double* MXi = (double*)ws;  ws += (size_t)B_ * HID_ * MODES_ * 8;
    double2* AB = (double2*)ws; ws += (size_t)B_ * HID_ * MODES_ * 16;
    double* Wb  = (double*)ws;  ws += (size_t)B_ * 576 * 8;
    double* Eb  = (double*)ws;  ws += (size_t)LAYERS_ * B_ * ED_ * 8;

    hipMemsetAsync(Eb, 0, (size_t)LAYERS_ * B_ * ED_ * 8, stream);

    dim3 blk(256);
    k_lift<<<dim3(S_ / 256, B_), blk, 0, stream>>>(x, lift_W, lift_b, h, sC);

    for (int lay = 0; lay < LAYERS_; ++lay) {
        k_hash<<<dim3(S_ / 256, B_), blk, 0, stream>>>(
            sC, sp_emb + (size_t)lay * NPSP_ * ED_, idx, Eb + (size_t)lay * B_ * ED_);
        k_dft<<<dim3(HID_ / 2, B_), blk, 0, stream>>>(h, Xr, Xi);
        k_mx<<<dim3(HEADS_, B_), blk, 0, stream>>>(
            Xr, Xi,
            mhf_Wr + (size_t)lay * HEADS_ * CH_ * CH_ * MODES_,
            mhf_Wi + (size_t)lay * HEADS_ * CH_ * CH_ * MODES_,
            MXr, MXi);
        k_gate<<<dim3(B_), blk, 0, stream>>>(
            Xr, Xi, MXr, MXi,
            fr_emb + (size_t)lay * NPFR_ * ED_,
            fr_W + (size_t)lay * ED_ * HID_ * MODES_,
            fr_b + (size_t)lay * HID_ * MODES_,
            Eb + (size_t)lay * B_ * ED_,
            sp_W + (size_t)lay * ED_ * HID_,
            sp_b + (size_t)lay * HID_,
            g_W1 + (size_t)lay * 192 * 64,
            g_b1 + (size_t)lay * 64,
            g_W2 + (size_t)lay * 64 * 3,
            g_b2 + (size_t)lay * 3,
            AB, Wb);
        k_recon<<<dim3(S_ / 256, B_), blk, 0, stream>>>(
            idx, sp_emb + (size_t)lay * NPSP_ * ED_, AB, Wb, h, sC);
    }

    k_proj<<<dim3(S_ / 256, B_), blk, 0, stream>>>(h, proj_W, proj_b, (float*)d_out);
}

// Round 4
// 847.382 us; speedup vs baseline: 1.9503x; 1.3068x over previous
//
#include <hip/hip_runtime.h>
#include <math.h>

#define B_ 16
#define CIN_ 3
#define HID_ 64
#define S_ 16384
#define MODES_ 16
#define HEADS_ 4
#define CH_ 16
#define ED_ 8
#define NPSP_ 500
#define NPFR_ 200
#define LAYERS_ 4
#define RECW_ 42                      // per-channel packed record, doubles
#define XCHUNK_ ((size_t)B_ * HID_ * MODES_)   // one partial-DFT chunk

// gelu(v), erf via 12-term odd Taylor in y=v/sqrt(2); |err|<2e-14 for |v|<=1,
// rare libm fallback. h stored f32 (3e-9 rounding) dominates — poly is free.
__device__ __forceinline__ double gelu_exact(double v) {
    double y = v * 0.70710678118654752440;
    double t = y * y;
    double p = -1.2290555301717926e-09;
    p = fma(p, t, 1.4807192815879218e-08);
    p = fma(p, t, -1.6365838718281893e-07);
    p = fma(p, t, 1.6462114365889246e-06);
    p = fma(p, t, -1.4925650358406251e-05);
    p = fma(p, t, 1.2055332981789664e-04);
    p = fma(p, t, -8.5483270234508528e-04);
    p = fma(p, t, 5.2239776254421878e-03);
    p = fma(p, t, -2.6866170645131252e-02);
    p = fma(p, t, 1.1283791670955126e-01);
    p = fma(p, t, -3.7612638903183752e-01);
    p = fma(p, t, 1.1283791670955126e+00);
    double er = y * p;
    if (t > 0.5000001) er = erf(y);
    return 0.5 * v * (1.0 + er);
}

// ---------------------------------------------------------------------------
// Lift: h[b,d,s] = sum_c x[b,c,s]*W[c,d] + bias[d]   (h f32, sC f64 unrounded)
// ---------------------------------------------------------------------------
__global__ __launch_bounds__(256) void k_lift(const float* __restrict__ x,
                                              const float* __restrict__ W,
                                              const float* __restrict__ bias,
                                              float* __restrict__ h,
                                              double* __restrict__ sC) {
    int b = blockIdx.y;
    int s = blockIdx.x * 256 + threadIdx.x;
    const float* xb = x + (size_t)b * CIN_ * S_ + s;
    double x0 = (double)xb[0];
    double x1 = (double)xb[S_];
    double x2 = (double)xb[2 * S_];
    float* hb = h + (size_t)b * HID_ * S_ + s;
    double acc = 0.0;
    for (int d = 0; d < HID_; ++d) {
        double v = x0 * (double)W[d];
        v = fma(x1, (double)W[HID_ + d], v);
        v = fma(x2, (double)W[2 * HID_ + d], v);
        v += (double)bias[d];
        hb[(size_t)d * S_] = (float)v;
        acc += v;
    }
    sC[(size_t)b * S_ + s] = acc;
}

// ---------------------------------------------------------------------------
// Spatial hash: wsum window, idx, block-reduced embedding sum (Eb).
// ---------------------------------------------------------------------------
__global__ __launch_bounds__(256) void k_hash(const double* __restrict__ sC,
                                              const float* __restrict__ emb_l,
                                              int* __restrict__ idx,
                                              double* __restrict__ Eb) {
    int b = blockIdx.y;
    int s0 = blockIdx.x * 256;
    int t = threadIdx.x;
    __shared__ double sl[260];
    for (int j = t; j < 260; j += 256) {
        int p = s0 - 2 + j;
        p = p < 0 ? 0 : (p > S_ - 1 ? S_ - 1 : p);
        sl[j] = sC[(size_t)b * S_ + p];
    }
    __syncthreads();
    double wsum = ((sl[t] + sl[t + 1]) + sl[t + 2]) + sl[t + 3];
    int ti = (int)(wsum * 31.0);
    int id = ti % NPSP_;
    if (id < 0) id += NPSP_;
    idx[(size_t)b * S_ + s0 + t] = id;

    const float* er = emb_l + id * ED_;
    double ev[8];
#pragma unroll
    for (int k = 0; k < 8; k++) ev[k] = (double)er[k];

    int lane = t & 63, wv = t >> 6;
    __shared__ double red[4][8];
#pragma unroll
    for (int k = 0; k < 8; k++) {
        double v = ev[k];
        for (int off = 32; off > 0; off >>= 1) v += __shfl_down(v, off, 64);
        if (lane == 0) red[wv][k] = v;
    }
    __syncthreads();
    if (t < 8) {
        double v = red[0][t] + red[1][t] + red[2][t] + red[3][t];
        atomicAdd(&Eb[b * ED_ + t], v);
    }
}

// ---------------------------------------------------------------------------
// 16-mode DFT, 2 channels/block, s-range split in 2 chunks (grid.y) for 2x
// latency-hiding waves. Deterministic: partials go to XrP[chunk][b][c][m].
// ---------------------------------------------------------------------------
__global__ __launch_bounds__(256) void k_dft(const float* __restrict__ h,
                                             double* __restrict__ XrP,
                                             double* __restrict__ XiP) {
    int b = blockIdx.z;
    int chunk = blockIdx.y;
    int c0 = blockIdx.x * 2;
    int t = threadIdx.x;
    int sbase = chunk * 8192 + t;
    const float* h0 = h + ((size_t)(b * HID_ + c0)) * S_ + sbase;
    const float* h1 = h0 + S_;

    double acc[64];
#pragma unroll
    for (int k = 0; k < 64; k++) acc[k] = 0.0;

    double cb = cospi((double)sbase / 8192.0);
    double sb = sinpi((double)sbase / 8192.0);
    const double CD = 0.99518472667219688624;  // cos(pi/32)
    const double SD = 0.09801714032956060199;  // sin(pi/32)

    for (int k = 0; k < 32; k++) {
        int s = k << 8;
        double hv0 = (double)h0[s];
        double hv1 = (double)h1[s];
        acc[0] += hv0;
        acc[32] += hv1;
        double c = cb, sv = sb;
#pragma unroll
        for (int m = 1; m < 16; m++) {
            acc[m]      = fma(hv0, c,  acc[m]);
            acc[16 + m] = fma(hv0, sv, acc[16 + m]);
            acc[32 + m] = fma(hv1, c,  acc[32 + m]);
            acc[48 + m] = fma(hv1, sv, acc[48 + m]);
            double cn = c * cb - sv * sb;
            double sn = sv * cb + c * sb;
            c = cn; sv = sn;
        }
        double c2 = cb * CD - sb * SD;
        double s2 = sb * CD + cb * SD;
        cb = c2; sb = s2;
    }

    int lane = t & 63, wv = t >> 6;
    __shared__ double red[4][64];
#pragma unroll
    for (int k = 0; k < 64; k++) {
        double v = acc[k];
        for (int off = 32; off > 0; off >>= 1) v += __shfl_down(v, off, 64);
        if (lane == 0) red[wv][k] = v;
    }
    __syncthreads();
    if (t < 64) {
        double v = red[0][t] + red[1][t] + red[2][t] + red[3][t];
        int cc = t >> 5, im = (t >> 4) & 1, m = t & 15;
        size_t o = chunk * XCHUNK_ + ((size_t)b * HID_ + c0 + cc) * MODES_ + m;
        if (im) XiP[o] = -v;
        else    XrP[o] = v;
    }
}

// ---------------------------------------------------------------------------
// MX complex head mixing, block per (head, b); sums the 2 DFT partials.
// ---------------------------------------------------------------------------
__global__ __launch_bounds__(256) void k_mx(const double* __restrict__ XrP,
                                            const double* __restrict__ XiP,
                                            const float* __restrict__ mWr,
                                            const float* __restrict__ mWi,
                                            double* __restrict__ MXr,
                                            double* __restrict__ MXi) {
    int hh = blockIdx.x, b = blockIdx.y, t = threadIdx.x;
    int o = t >> 4, m = t & 15;
    size_t xb = ((size_t)b * HID_ + hh * CH_) * MODES_;
    const float* wr = mWr + (size_t)hh * CH_ * CH_ * MODES_;
    const float* wi = mWi + (size_t)hh * CH_ * CH_ * MODES_;
    double aR = 0.0, aI = 0.0;
#pragma unroll 4
    for (int i = 0; i < CH_; i++) {
        double xrv = XrP[xb + i * MODES_ + m] + XrP[XCHUNK_ + xb + i * MODES_ + m];
        double xiv = XiP[xb + i * MODES_ + m] + XiP[XCHUNK_ + xb + i * MODES_ + m];
        double wrv = (double)wr[(i * CH_ + o) * MODES_ + m];
        double wiv = (double)wi[(i * CH_ + o) * MODES_ + m];
        aR += xrv * wrv - xiv * wiv;
        aI += xrv * wiv + xiv * wrv;
    }
    int co = hh * CH_ + o;
    MXr[(size_t)b * 1024 + co * MODES_ + m] = aR;
    MXi[(size_t)b * 1024 + co * MODES_ + m] = aI;
}

// ---------------------------------------------------------------------------
// Gate/pack: mag/fidx, P, means, gating MLP, softmax -> PACKED per-c records
//   REC[b][c][0..31]  = AB pairs: {k_m*(w1*MXr+w2*P), m? -k_m*w1*MXi : 0}
//   REC[b][c][32..39] = w0*sp_W[e][c];  REC[b][c][40] = w0*sp_b[c]; [41]=0
// ---------------------------------------------------------------------------
__global__ __launch_bounds__(256) void k_gate(const double* __restrict__ XrP,
                                              const double* __restrict__ XiP,
                                              const double* __restrict__ MXr,
                                              const double* __restrict__ MXi,
                                              const float* __restrict__ fr_emb_l,
                                              const float* __restrict__ fr_W_l,
                                              const float* __restrict__ fr_b_l,
                                              const double* __restrict__ Eb,
                                              const float* __restrict__ sp_W_l,
                                              const float* __restrict__ sp_b_l,
                                              const float* __restrict__ gW1,
                                              const float* __restrict__ gb1,
                                              const float* __restrict__ gW2,
                                              const float* __restrict__ gb2,
                                              double* __restrict__ RECg) {
    int b = blockIdx.x;
    int t = threadIdx.x;
    __shared__ double sP[HID_ * MODES_];
    __shared__ double gg[192], h1s[64], sww[3];
    __shared__ int magI[MODES_];
    __shared__ int fidxS;

    if (t < MODES_) {
        double acc = 0.0;
        for (int c = 0; c < HID_; c++) {
            size_t o = (size_t)b * 1024 + c * MODES_ + t;
            double re = XrP[o] + XrP[XCHUNK_ + o];
            double im = XiP[o] + XiP[XCHUNK_ + o];
            acc += sqrt(re * re + im * im);
        }
        magI[t] = (int)(acc * (1.0 / 64.0) * 1000.0);
    }
    __syncthreads();
    if (t == 0) {
        int ssum = 0;
        for (int m = 0; m < MODES_; m++) ssum += magI[m];
        int f = ssum % NPFR_;
        if (f < 0) f += NPFR_;
        fidxS = f;
    }
    __syncthreads();

    {
        const float* fe = fr_emb_l + fidxS * ED_;
        for (int u = t; u < HID_ * MODES_; u += 256) {
            double acc = 0.0;
            for (int e = 0; e < ED_; e++)
                acc += (double)fe[e] * (double)fr_W_l[e * (HID_ * MODES_) + u];
            sP[u] = acc + (double)fr_b_l[u];
        }
    }
    __syncthreads();

    if (t < 64) {
        double a = 0.0;
        for (int e = 0; e < ED_; e++)
            a += Eb[b * ED_ + e] * (double)sp_W_l[e * 64 + t];
        gg[t]       = a * (1.0 / 16384.0) + (double)sp_b_l[t];
        gg[64 + t]  = MXr[(size_t)b * 1024 + t * MODES_] * (1.0 / 16384.0);
        gg[128 + t] = sP[t * MODES_] * (1.0 / 16384.0);
    }
    __syncthreads();
    if (t < 64) {
        double a = 0.0;
        for (int k = 0; k < 192; k++) a += gg[k] * (double)gW1[k * 64 + t];
        a += (double)gb1[t];
        h1s[t] = a > 0.0 ? a : 0.0;
    }
    __syncthreads();
    if (t == 0) {
        double l[3];
        for (int j = 0; j < 3; j++) {
            double a = 0.0;
            for (int k = 0; k < 64; k++) a += h1s[k] * (double)gW2[k * 3 + j];
            l[j] = a + (double)gb2[j];
        }
        double mx = fmax(l[0], fmax(l[1], l[2]));
        double e0 = exp(l[0] - mx), e1 = exp(l[1] - mx), e2 = exp(l[2] - mx);
        double sum = e0 + e1 + e2;
        sww[0] = e0 / sum; sww[1] = e1 / sum; sww[2] = e2 / sum;
    }
    __syncthreads();

    double w0s = sww[0], w1s = sww[1], w2s = sww[2];
    double* R = RECg + (size_t)b * HID_ * RECW_;
    for (int u = t; u < HID_ * MODES_; u += 256) {
        int c = u >> 4, m = u & 15;
        double km = (m == 0 ? 1.0 : 2.0) * (1.0 / 16384.0);
        R[c * RECW_ + 2 * m]     = km * (w1s * MXr[(size_t)b * 1024 + u] + w2s * sP[u]);
        R[c * RECW_ + 2 * m + 1] = (m == 0) ? 0.0 : -(km * w1s * MXi[(size_t)b * 1024 + u]);
    }
    for (int u = t; u < 512; u += 256) {
        int e = u >> 6, c = u & 63;
        R[c * RECW_ + 32 + e] = w0s * (double)sp_W_l[u];
    }
    if (t < 64) {
        R[t * RECW_ + 40] = w0s * (double)sp_b_l[t];
        R[t * RECW_ + 41] = 0.0;
    }
}

// ---------------------------------------------------------------------------
// Reconstruction: 1 position/thread, all coefficients in LDS (broadcast
// ds_reads overlap the fp64 pipe — round-1-proven mechanism, fused math).
// Per c: 1+21 LDS issues, 41 fp64 fma + gelu. LDS: 21 KB rec + 18 KB semb.
// ---------------------------------------------------------------------------
__global__ __launch_bounds__(256) void k_recon(const int* __restrict__ idx,
                                               const float* __restrict__ sp_emb_l,
                                               const double* __restrict__ RECg,
                                               float* __restrict__ h,
                                               double* __restrict__ sC) {
    int b = blockIdx.y;
    int s = blockIdx.x * 256 + threadIdx.x;
    int t = threadIdx.x;
    __shared__ double rec[HID_ * RECW_];   // 21 KB, per-c stride 336 B (b128-aligned)
    __shared__ float semb[NPSP_ * 9];      // 18 KB, stride 9
    for (int j = t; j < HID_ * RECW_; j += 256)
        rec[j] = RECg[(size_t)b * HID_ * RECW_ + j];
    for (int j = t; j < NPSP_ * 8; j += 256) {
        int r = j >> 3, e2 = j & 7;
        semb[r * 9 + e2] = sp_emb_l[j];
    }
    __syncthreads();

    int id = idx[(size_t)b * S_ + s];
    double e[8];
#pragma unroll
    for (int k = 0; k < 8; k++) e[k] = (double)semb[id * 9 + k];

    double cb = cospi((double)s / 8192.0);
    double sb = sinpi((double)s / 8192.0);
    double cm[16], sm[16];
    cm[0] = 1.0; sm[0] = 0.0;
    cm[1] = cb;  sm[1] = sb;
#pragma unroll
    for (int m = 2; m < 16; m++) {
        cm[m] = cm[m - 1] * cb - sm[m - 1] * sb;
        sm[m] = sm[m - 1] * cb + cm[m - 1] * sb;
    }

    float* hb = h + (size_t)b * HID_ * S_ + s;
    double csum = 0.0;
    for (int c = 0; c < HID_; c++) {
        const double2* r2 = (const double2*)(rec + c * RECW_);
        double v = rec[c * RECW_ + 40];
#pragma unroll
        for (int k = 0; k < 4; k++) {
            double2 w = r2[16 + k];
            v = fma(e[2 * k], w.x, v);
            v = fma(e[2 * k + 1], w.y, v);
        }
#pragma unroll
        for (int m = 0; m < 16; m++) {
            double2 q = r2[m];
            v = fma(q.x, cm[m], v);
            v = fma(q.y, sm[m], v);
        }
        double g = gelu_exact(v);
        hb[(size_t)c * S_] = (float)g;
        csum += g;
    }
    sC[(size_t)b * S_ + s] = csum;
}

// ---------------------------------------------------------------------------
// Projection: out[b,s] = sum_d h[b,d,s]*pW[d] + pb
// ---------------------------------------------------------------------------
__global__ __launch_bounds__(256) void k_proj(const float* __restrict__ h,
                                              const float* __restrict__ pW,
                                              const float* __restrict__ pb,
                                              float* __restrict__ out) {
    int b = blockIdx.y;
    int s = blockIdx.x * 256 + threadIdx.x;
    const float* hb = h + (size_t)b * HID_ * S_ + s;
    double acc = 0.0;
    for (int d = 0; d < HID_; d++)
        acc += (double)hb[(size_t)d * S_] * (double)pW[d];
    out[(size_t)b * S_ + s] = (float)(acc + (double)pb[0]);
}

extern "C" void kernel_launch(void* const* d_in, const int* in_sizes, int n_in,
                              void* d_out, int out_size, void* d_ws, size_t ws_size,
                              hipStream_t stream) {
    const float* x      = (const float*)d_in[0];
    const float* lift_W = (const float*)d_in[1];
    const float* lift_b = (const float*)d_in[2];
    const float* proj_W = (const float*)d_in[3];
    const float* proj_b = (const float*)d_in[4];
    const float* sp_emb = (const float*)d_in[5];
    const float* sp_W   = (const float*)d_in[6];
    const float* sp_b   = (const float*)d_in[7];
    const float* fr_emb = (const float*)d_in[8];
    const float* fr_W   = (const float*)d_in[9];
    const float* fr_b   = (const float*)d_in[10];
    const float* g_W1   = (const float*)d_in[11];
    const float* g_b1   = (const float*)d_in[12];
    const float* g_W2   = (const float*)d_in[13];
    const float* g_b2   = (const float*)d_in[14];
    const float* mhf_Wr = (const float*)d_in[15];
    const float* mhf_Wi = (const float*)d_in[16];

    char* ws = (char*)d_ws;
    float* h    = (float*)ws;   ws += (size_t)B_ * HID_ * S_ * 4;   // 64 MiB
    double* sC  = (double*)ws;  ws += (size_t)B_ * S_ * 8;          // 2 MiB
    int* idx    = (int*)ws;     ws += (size_t)B_ * S_ * 4;          // 1 MiB
    double* XrP = (double*)ws;  ws += 2 * XCHUNK_ * 8;              // 256 KiB
    double* XiP = (double*)ws;  ws += 2 * XCHUNK_ * 8;              // 256 KiB
    double* MXr = (double*)ws;  ws += (size_t)B_ * HID_ * MODES_ * 8;
    double* MXi = (double*)ws;  ws += (size_t)B_ * HID_ * MODES_ * 8;
    double* REC = (double*)ws;  ws += (size_t)B_ * HID_ * RECW_ * 8;
    double* Eb  = (double*)ws;  ws += (size_t)LAYERS_ * B_ * ED_ * 8;

    hipMemsetAsync(Eb, 0, (size_t)LAYERS_ * B_ * ED_ * 8, stream);

    dim3 blk(256);
    k_lift<<<dim3(S_ / 256, B_), blk, 0, stream>>>(x, lift_W, lift_b, h, sC);

    for (int lay = 0; lay < LAYERS_; ++lay) {
        k_hash<<<dim3(S_ / 256, B_), blk, 0, stream>>>(
            sC, sp_emb + (size_t)lay * NPSP_ * ED_, idx, Eb + (size_t)lay * B_ * ED_);
        k_dft<<<dim3(HID_ / 2, 2, B_), blk, 0, stream>>>(h, XrP, XiP);
        k_mx<<<dim3(HEADS_, B_), blk, 0, stream>>>(
            XrP, XiP,
            mhf_Wr + (size_t)lay * HEADS_ * CH_ * CH_ * MODES_,
            mhf_Wi + (size_t)lay * HEADS_ * CH_ * CH_ * MODES_,
            MXr, MXi);
        k_gate<<<dim3(B_), blk, 0, stream>>>(
            XrP, XiP, MXr, MXi,
            fr_emb + (size_t)lay * NPFR_ * ED_,
            fr_W + (size_t)lay * ED_ * HID_ * MODES_,
            fr_b + (size_t)lay * HID_ * MODES_,
            Eb + (size_t)lay * B_ * ED_,
            sp_W + (size_t)lay * ED_ * HID_,
            sp_b + (size_t)lay * HID_,
            g_W1 + (size_t)lay * 192 * 64,
            g_b1 + (size_t)lay * 64,
            g_W2 + (size_t)lay * 64 * 3,
            g_b2 + (size_t)lay * 3,
            REC);
        k_recon<<<dim3(S_ / 256, B_), blk, 0, stream>>>(
            idx, sp_emb + (size_t)lay * NPSP_ * ED_, REC, h, sC);
    }

    k_proj<<<dim3(S_ / 256, B_), blk, 0, stream>>>(h, proj_W, proj_b, (float*)d_out);
}

// Round 5
// 650.255 us; speedup vs baseline: 2.5416x; 1.3032x over previous
//
#include <hip/hip_runtime.h>
#include <math.h>

#define B_ 16
#define CIN_ 3
#define HID_ 64
#define S_ 16384
#define MODES_ 16
#define HEADS_ 4
#define CH_ 16
#define ED_ 8
#define NPSP_ 500
#define NPFR_ 200
#define LAYERS_ 4
#define RECW_ 42                      // per-channel packed record, doubles

// gelu(v), erf via 12-term odd Taylor in y=v/sqrt(2); |err|<2e-14 for |v|<=1,
// rare libm fallback. h stored f32 (3e-9 rounding) dominates — poly is free.
__device__ __forceinline__ double gelu_exact(double v) {
    double y = v * 0.70710678118654752440;
    double t = y * y;
    double p = -1.2290555301717926e-09;
    p = fma(p, t, 1.4807192815879218e-08);
    p = fma(p, t, -1.6365838718281893e-07);
    p = fma(p, t, 1.6462114365889246e-06);
    p = fma(p, t, -1.4925650358406251e-05);
    p = fma(p, t, 1.2055332981789664e-04);
    p = fma(p, t, -8.5483270234508528e-04);
    p = fma(p, t, 5.2239776254421878e-03);
    p = fma(p, t, -2.6866170645131252e-02);
    p = fma(p, t, 1.1283791670955126e-01);
    p = fma(p, t, -3.7612638903183752e-01);
    p = fma(p, t, 1.1283791670955126e+00);
    double er = y * p;
    if (t > 0.5000001) er = erf(y);
    return 0.5 * v * (1.0 + er);
}

// cos(m*pi/32), sin(m*pi/32), m = 0..15
__device__ __constant__ double KC_[16] = {1.0, 0.99518472667219688624,
    0.98078528040323044913, 0.95694033573220886494, 0.92387953251128675613,
    0.88192126434835502971, 0.83146961230254523708, 0.77301045336273696081,
    0.70710678118654752440, 0.63439328416364549822, 0.55557023301960222474,
    0.47139673682599764856, 0.38268343236508977173, 0.29028467725446236764,
    0.19509032201612826785, 0.09801714032956060199};
__device__ __constant__ double KS_[16] = {0.0, 0.09801714032956060199,
    0.19509032201612826785, 0.29028467725446236764, 0.38268343236508977173,
    0.47139673682599764856, 0.55557023301960222474, 0.63439328416364549822,
    0.70710678118654752440, 0.77301045336273696081, 0.83146961230254523708,
    0.88192126434835502971, 0.92387953251128675613, 0.95694033573220886494,
    0.98078528040323044913, 0.99518472667219688624};

// ---------------------------------------------------------------------------
// Lift: h[b,d,s] = sum_c x[b,c,s]*W[c,d] + bias[d]   (h f32, sC f64 unrounded)
// ---------------------------------------------------------------------------
__global__ __launch_bounds__(256) void k_lift(const float* __restrict__ x,
                                              const float* __restrict__ W,
                                              const float* __restrict__ bias,
                                              float* __restrict__ h,
                                              double* __restrict__ sC) {
    int b = blockIdx.y;
    int s = blockIdx.x * 256 + threadIdx.x;
    const float* xb = x + (size_t)b * CIN_ * S_ + s;
    double x0 = (double)xb[0];
    double x1 = (double)xb[S_];
    double x2 = (double)xb[2 * S_];
    float* hb = h + (size_t)b * HID_ * S_ + s;
    double acc = 0.0;
    for (int d = 0; d < HID_; ++d) {
        double v = x0 * (double)W[d];
        v = fma(x1, (double)W[HID_ + d], v);
        v = fma(x2, (double)W[2 * HID_ + d], v);
        v += (double)bias[d];
        hb[(size_t)d * S_] = (float)v;
        acc += v;
    }
    sC[(size_t)b * S_ + s] = acc;
}

// ---------------------------------------------------------------------------
// Spatial hash: wsum window, idx, block-reduced embedding sum (Eb).
// ---------------------------------------------------------------------------
__global__ __launch_bounds__(256) void k_hash(const double* __restrict__ sC,
                                              const float* __restrict__ emb_l,
                                              int* __restrict__ idx,
                                              double* __restrict__ Eb) {
    int b = blockIdx.y;
    int s0 = blockIdx.x * 256;
    int t = threadIdx.x;
    __shared__ double sl[260];
    for (int j = t; j < 260; j += 256) {
        int p = s0 - 2 + j;
        p = p < 0 ? 0 : (p > S_ - 1 ? S_ - 1 : p);
        sl[j] = sC[(size_t)b * S_ + p];
    }
    __syncthreads();
    double wsum = ((sl[t] + sl[t + 1]) + sl[t + 2]) + sl[t + 3];
    int ti = (int)(wsum * 31.0);
    int id = ti % NPSP_;
    if (id < 0) id += NPSP_;
    idx[(size_t)b * S_ + s0 + t] = id;

    const float* er = emb_l + id * ED_;
    double ev[8];
#pragma unroll
    for (int k = 0; k < 8; k++) ev[k] = (double)er[k];

    int lane = t & 63, wv = t >> 6;
    __shared__ double red[4][8];
#pragma unroll
    for (int k = 0; k < 8; k++) {
        double v = ev[k];
        for (int off = 32; off > 0; off >>= 1) v += __shfl_down(v, off, 64);
        if (lane == 0) red[wv][k] = v;
    }
    __syncthreads();
    if (t < 8) {
        double v = red[0][t] + red[1][t] + red[2][t] + red[3][t];
        atomicAdd(&Eb[b * ED_ + t], v);
    }
}

// ---------------------------------------------------------------------------
// 16-mode DFT, radix-4 decimation: v_m(s) = h[s] + (-i)^m h[s+S/4]
// + (-1)^m h[s+S/2] + (i)^m h[s+3S/4], summed over s<S/4 with e^{-i2pims/S}.
// Per-mode INDEPENDENT twiddle pairs rotated by constant m*pi/32 each k-step
// (no serial m-chain). 2 channels/block, grid (32,B)=512 blocks = 2/CU.
// ---------------------------------------------------------------------------
__global__ __launch_bounds__(256, 2) void k_dft(const float* __restrict__ h,
                                                double* __restrict__ Xr,
                                                double* __restrict__ Xi) {
    int b = blockIdx.y;
    int c0 = blockIdx.x * 2;
    int t = threadIdx.x;
    const float* h0 = h + ((size_t)(b * HID_ + c0)) * S_ + t;
    const float* h1 = h0 + S_;

    // acc[m]=ch0 cos, acc[16+m]=ch0 sin, acc[32+m]=ch1 cos, acc[48+m]=ch1 sin
    double acc[64];
#pragma unroll
    for (int k = 0; k < 64; k++) acc[k] = 0.0;

    // init per-mode twiddles for s = t via one-time recurrence
    double cmv[16], smv[16];
    cmv[0] = 1.0; smv[0] = 0.0;
    cmv[1] = cospi((double)t / 8192.0);
    smv[1] = sinpi((double)t / 8192.0);
#pragma unroll
    for (int m = 2; m < 16; m++) {
        cmv[m] = cmv[m - 1] * cmv[1] - smv[m - 1] * smv[1];
        smv[m] = smv[m - 1] * cmv[1] + cmv[m - 1] * smv[1];
    }

    for (int k = 0; k < 16; k++) {
        int s = k << 8;
        double a0 = (double)h0[s];
        double b0 = (double)h0[s + 4096];
        double c0v = (double)h0[s + 8192];
        double d0 = (double)h0[s + 12288];
        double a1 = (double)h1[s];
        double b1 = (double)h1[s + 4096];
        double c1v = (double)h1[s + 8192];
        double d1 = (double)h1[s + 12288];

        double t10 = a0 + c0v, t20 = b0 + d0;
        double g00 = t10 + t20, g20 = t10 - t20;
        double ar0 = a0 - c0v, br0 = b0 - d0;
        double t11 = a1 + c1v, t21 = b1 + d1;
        double g01 = t11 + t21, g21 = t11 - t21;
        double ar1 = a1 - c1v, br1 = b1 - d1;

        acc[0] += g00;
        acc[32] += g01;
#pragma unroll
        for (int m = 1; m < 16; m++) {
            double c = cmv[m], s_ = smv[m];
            if ((m & 1) == 0) {
                double g0x = (m & 2) ? g20 : g00;
                double g1x = (m & 2) ? g21 : g01;
                acc[m]      = fma(g0x, c,  acc[m]);
                acc[16 + m] = fma(g0x, s_, acc[16 + m]);
                acc[32 + m] = fma(g1x, c,  acc[32 + m]);
                acc[48 + m] = fma(g1x, s_, acc[48 + m]);
            } else if ((m & 2) == 0) {   // m ≡ 1 (mod 4): v = ar - i*br
                acc[m]      = fma(ar0, c,  fma(-br0, s_, acc[m]));
                acc[16 + m] = fma(ar0, s_, fma( br0, c,  acc[16 + m]));
                acc[32 + m] = fma(ar1, c,  fma(-br1, s_, acc[32 + m]));
                acc[48 + m] = fma(ar1, s_, fma( br1, c,  acc[48 + m]));
            } else {                      // m ≡ 3 (mod 4): v = ar + i*br
                acc[m]      = fma(ar0, c,  fma( br0, s_, acc[m]));
                acc[16 + m] = fma(ar0, s_, fma(-br0, c,  acc[16 + m]));
                acc[32 + m] = fma(ar1, c,  fma( br1, s_, acc[32 + m]));
                acc[48 + m] = fma(ar1, s_, fma(-br1, c,  acc[48 + m]));
            }
        }
        // rotate all modes by m*pi/32 (independent, ILP-rich)
#pragma unroll
        for (int m = 1; m < 16; m++) {
            double cn = cmv[m] * KC_[m] - smv[m] * KS_[m];
            double sn = smv[m] * KC_[m] + cmv[m] * KS_[m];
            cmv[m] = cn; smv[m] = sn;
        }
    }

    int lane = t & 63, wv = t >> 6;
    __shared__ double red[4][64];
#pragma unroll
    for (int k = 0; k < 64; k++) {
        double v = acc[k];
        for (int off = 32; off > 0; off >>= 1) v += __shfl_down(v, off, 64);
        if (lane == 0) red[wv][k] = v;
    }
    __syncthreads();
    if (t < 64) {
        double v = red[0][t] + red[1][t] + red[2][t] + red[3][t];
        int cc = t >> 5, im = (t >> 4) & 1, m = t & 15;
        size_t o = ((size_t)b * HID_ + c0 + cc) * MODES_ + m;
        if (im) Xi[o] = -v;
        else    Xr[o] = v;
    }
}

// ---------------------------------------------------------------------------
// MX complex head mixing, block per (head, b).
// ---------------------------------------------------------------------------
__global__ __launch_bounds__(256) void k_mx(const double* __restrict__ Xr,
                                            const double* __restrict__ Xi,
                                            const float* __restrict__ mWr,
                                            const float* __restrict__ mWi,
                                            double* __restrict__ MXr,
                                            double* __restrict__ MXi) {
    int hh = blockIdx.x, b = blockIdx.y, t = threadIdx.x;
    int o = t >> 4, m = t & 15;
    size_t xb = ((size_t)b * HID_ + hh * CH_) * MODES_;
    const float* wr = mWr + (size_t)hh * CH_ * CH_ * MODES_;
    const float* wi = mWi + (size_t)hh * CH_ * CH_ * MODES_;
    double aR = 0.0, aI = 0.0;
#pragma unroll 4
    for (int i = 0; i < CH_; i++) {
        double xrv = Xr[xb + i * MODES_ + m];
        double xiv = Xi[xb + i * MODES_ + m];
        double wrv = (double)wr[(i * CH_ + o) * MODES_ + m];
        double wiv = (double)wi[(i * CH_ + o) * MODES_ + m];
        aR += xrv * wrv - xiv * wiv;
        aI += xrv * wiv + xiv * wrv;
    }
    int co = hh * CH_ + o;
    MXr[(size_t)b * 1024 + co * MODES_ + m] = aR;
    MXi[(size_t)b * 1024 + co * MODES_ + m] = aI;
}

// ---------------------------------------------------------------------------
// Gate/pack: mag/fidx, P, means, gating MLP, softmax -> PACKED per-c records
//   REC[b][c][0..31]  = AB pairs: {k_m*(w1*MXr+w2*P), m? -k_m*w1*MXi : 0}
//   REC[b][c][32..39] = w0*sp_W[e][c];  REC[b][c][40] = w0*sp_b[c]; [41]=0
// ---------------------------------------------------------------------------
__global__ __launch_bounds__(256) void k_gate(const double* __restrict__ Xr,
                                              const double* __restrict__ Xi,
                                              const double* __restrict__ MXr,
                                              const double* __restrict__ MXi,
                                              const float* __restrict__ fr_emb_l,
                                              const float* __restrict__ fr_W_l,
                                              const float* __restrict__ fr_b_l,
                                              const double* __restrict__ Eb,
                                              const float* __restrict__ sp_W_l,
                                              const float* __restrict__ sp_b_l,
                                              const float* __restrict__ gW1,
                                              const float* __restrict__ gb1,
                                              const float* __restrict__ gW2,
                                              const float* __restrict__ gb2,
                                              double* __restrict__ RECg) {
    int b = blockIdx.x;
    int t = threadIdx.x;
    __shared__ double sP[HID_ * MODES_];
    __shared__ double gg[192], h1s[64], sww[3];
    __shared__ int magI[MODES_];
    __shared__ int fidxS;

    if (t < MODES_) {
        double acc = 0.0;
        for (int c = 0; c < HID_; c++) {
            size_t o = (size_t)b * 1024 + c * MODES_ + t;
            double re = Xr[o];
            double im = Xi[o];
            acc += sqrt(re * re + im * im);
        }
        magI[t] = (int)(acc * (1.0 / 64.0) * 1000.0);
    }
    __syncthreads();
    if (t == 0) {
        int ssum = 0;
        for (int m = 0; m < MODES_; m++) ssum += magI[m];
        int f = ssum % NPFR_;
        if (f < 0) f += NPFR_;
        fidxS = f;
    }
    __syncthreads();

    {
        const float* fe = fr_emb_l + fidxS * ED_;
        for (int u = t; u < HID_ * MODES_; u += 256) {
            double acc = 0.0;
            for (int e = 0; e < ED_; e++)
                acc += (double)fe[e] * (double)fr_W_l[e * (HID_ * MODES_) + u];
            sP[u] = acc + (double)fr_b_l[u];
        }
    }
    __syncthreads();

    if (t < 64) {
        double a = 0.0;
        for (int e = 0; e < ED_; e++)
            a += Eb[b * ED_ + e] * (double)sp_W_l[e * 64 + t];
        gg[t]       = a * (1.0 / 16384.0) + (double)sp_b_l[t];
        gg[64 + t]  = MXr[(size_t)b * 1024 + t * MODES_] * (1.0 / 16384.0);
        gg[128 + t] = sP[t * MODES_] * (1.0 / 16384.0);
    }
    __syncthreads();
    if (t < 64) {
        double a = 0.0;
        for (int k = 0; k < 192; k++) a += gg[k] * (double)gW1[k * 64 + t];
        a += (double)gb1[t];
        h1s[t] = a > 0.0 ? a : 0.0;
    }
    __syncthreads();
    if (t == 0) {
        double l[3];
        for (int j = 0; j < 3; j++) {
            double a = 0.0;
            for (int k = 0; k < 64; k++) a += h1s[k] * (double)gW2[k * 3 + j];
            l[j] = a + (double)gb2[j];
        }
        double mx = fmax(l[0], fmax(l[1], l[2]));
        double e0 = exp(l[0] - mx), e1 = exp(l[1] - mx), e2 = exp(l[2] - mx);
        double sum = e0 + e1 + e2;
        sww[0] = e0 / sum; sww[1] = e1 / sum; sww[2] = e2 / sum;
    }
    __syncthreads();

    double w0s = sww[0], w1s = sww[1], w2s = sww[2];
    double* R = RECg + (size_t)b * HID_ * RECW_;
    for (int u = t; u < HID_ * MODES_; u += 256) {
        int c = u >> 4, m = u & 15;
        double km = (m == 0 ? 1.0 : 2.0) * (1.0 / 16384.0);
        R[c * RECW_ + 2 * m]     = km * (w1s * MXr[(size_t)b * 1024 + u] + w2s * sP[u]);
        R[c * RECW_ + 2 * m + 1] = (m == 0) ? 0.0 : -(km * w1s * MXi[(size_t)b * 1024 + u]);
    }
    for (int u = t; u < 512; u += 256) {
        int e = u >> 6, c = u & 63;
        R[c * RECW_ + 32 + e] = w0s * (double)sp_W_l[u];
    }
    if (t < 64) {
        R[t * RECW_ + 40] = w0s * (double)sp_b_l[t];
        R[t * RECW_ + 41] = 0.0;
    }
}

// ---------------------------------------------------------------------------
// Reconstruction: 1 position/thread, packed per-c LDS records (broadcast
// ds_reads overlap the fp64 pipe). Per c: 21 LDS issues, 41 fma + gelu.
// ---------------------------------------------------------------------------
__global__ __launch_bounds__(256) void k_recon(const int* __restrict__ idx,
                                               const float* __restrict__ sp_emb_l,
                                               const double* __restrict__ RECg,
                                               float* __restrict__ h,
                                               double* __restrict__ sC) {
    int b = blockIdx.y;
    int s = blockIdx.x * 256 + threadIdx.x;
    int t = threadIdx.x;
    __shared__ double rec[HID_ * RECW_];   // 21 KB
    __shared__ float semb[NPSP_ * 9];      // 18 KB, stride 9
    for (int j = t; j < HID_ * RECW_; j += 256)
        rec[j] = RECg[(size_t)b * HID_ * RECW_ + j];
    for (int j = t; j < NPSP_ * 8; j += 256) {
        int r = j >> 3, e2 = j & 7;
        semb[r * 9 + e2] = sp_emb_l[j];
    }
    __syncthreads();

    int id = idx[(size_t)b * S_ + s];
    double e[8];
#pragma unroll
    for (int k = 0; k < 8; k++) e[k] = (double)semb[id * 9 + k];

    double cb = cospi((double)s / 8192.0);
    double sb = sinpi((double)s / 8192.0);
    double cm[16], sm[16];
    cm[0] = 1.0; sm[0] = 0.0;
    cm[1] = cb;  sm[1] = sb;
#pragma unroll
    for (int m = 2; m < 16; m++) {
        cm[m] = cm[m - 1] * cb - sm[m - 1] * sb;
        sm[m] = sm[m - 1] * cb + cm[m - 1] * sb;
    }

    float* hb = h + (size_t)b * HID_ * S_ + s;
    double csum = 0.0;
    for (int c = 0; c < HID_; c++) {
        const double2* r2 = (const double2*)(rec + c * RECW_);
        double v = rec[c * RECW_ + 40];
#pragma unroll
        for (int k = 0; k < 4; k++) {
            double2 w = r2[16 + k];
            v = fma(e[2 * k], w.x, v);
            v = fma(e[2 * k + 1], w.y, v);
        }
#pragma unroll
        for (int m = 0; m < 16; m++) {
            double2 q = r2[m];
            v = fma(q.x, cm[m], v);
            v = fma(q.y, sm[m], v);
        }
        double g = gelu_exact(v);
        hb[(size_t)c * S_] = (float)g;
        csum += g;
    }
    sC[(size_t)b * S_ + s] = csum;
}

// ---------------------------------------------------------------------------
// Projection: out[b,s] = sum_d h[b,d,s]*pW[d] + pb
// ---------------------------------------------------------------------------
__global__ __launch_bounds__(256) void k_proj(const float* __restrict__ h,
                                              const float* __restrict__ pW,
                                              const float* __restrict__ pb,
                                              float* __restrict__ out) {
    int b = blockIdx.y;
    int s = blockIdx.x * 256 + threadIdx.x;
    const float* hb = h + (size_t)b * HID_ * S_ + s;
    double acc = 0.0;
    for (int d = 0; d < HID_; d++)
        acc += (double)hb[(size_t)d * S_] * (double)pW[d];
    out[(size_t)b * S_ + s] = (float)(acc + (double)pb[0]);
}

extern "C" void kernel_launch(void* const* d_in, const int* in_sizes, int n_in,
                              void* d_out, int out_size, void* d_ws, size_t ws_size,
                              hipStream_t stream) {
    const float* x      = (const float*)d_in[0];
    const float* lift_W = (const float*)d_in[1];
    const float* lift_b = (const float*)d_in[2];
    const float* proj_W = (const float*)d_in[3];
    const float* proj_b = (const float*)d_in[4];
    const float* sp_emb = (const float*)d_in[5];
    const float* sp_W   = (const float*)d_in[6];
    const float* sp_b   = (const float*)d_in[7];
    const float* fr_emb = (const float*)d_in[8];
    const float* fr_W   = (const float*)d_in[9];
    const float* fr_b   = (const float*)d_in[10];
    const float* g_W1   = (const float*)d_in[11];
    const float* g_b1   = (const float*)d_in[12];
    const float* g_W2   = (const float*)d_in[13];
    const float* g_b2   = (const float*)d_in[14];
    const float* mhf_Wr = (const float*)d_in[15];
    const float* mhf_Wi = (const float*)d_in[16];

    char* ws = (char*)d_ws;
    float* h    = (float*)ws;   ws += (size_t)B_ * HID_ * S_ * 4;   // 64 MiB
    double* sC  = (double*)ws;  ws += (size_t)B_ * S_ * 8;          // 2 MiB
    int* idx    = (int*)ws;     ws += (size_t)B_ * S_ * 4;          // 1 MiB
    double* Xr  = (double*)ws;  ws += (size_t)B_ * HID_ * MODES_ * 8;
    double* Xi  = (double*)ws;  ws += (size_t)B_ * HID_ * MODES_ * 8;
    double* MXr = (double*)ws;  ws += (size_t)B_ * HID_ * MODES_ * 8;
    double* MXi = (double*)ws;  ws += (size_t)B_ * HID_ * MODES_ * 8;
    double* REC = (double*)ws;  ws += (size_t)B_ * HID_ * RECW_ * 8;
    double* Eb  = (double*)ws;  ws += (size_t)LAYERS_ * B_ * ED_ * 8;

    hipMemsetAsync(Eb, 0, (size_t)LAYERS_ * B_ * ED_ * 8, stream);

    dim3 blk(256);
    k_lift<<<dim3(S_ / 256, B_), blk, 0, stream>>>(x, lift_W, lift_b, h, sC);

    for (int lay = 0; lay < LAYERS_; ++lay) {
        k_hash<<<dim3(S_ / 256, B_), blk, 0, stream>>>(
            sC, sp_emb + (size_t)lay * NPSP_ * ED_, idx, Eb + (size_t)lay * B_ * ED_);
        k_dft<<<dim3(HID_ / 2, B_), blk, 0, stream>>>(h, Xr, Xi);
        k_mx<<<dim3(HEADS_, B_), blk, 0, stream>>>(
            Xr, Xi,
            mhf_Wr + (size_t)lay * HEADS_ * CH_ * CH_ * MODES_,
            mhf_Wi + (size_t)lay * HEADS_ * CH_ * CH_ * MODES_,
            MXr, MXi);
        k_gate<<<dim3(B_), blk, 0, stream>>>(
            Xr, Xi, MXr, MXi,
            fr_emb + (size_t)lay * NPFR_ * ED_,
            fr_W + (size_t)lay * ED_ * HID_ * MODES_,
            fr_b + (size_t)lay * HID_ * MODES_,
            Eb + (size_t)lay * B_ * ED_,
            sp_W + (size_t)lay * ED_ * HID_,
            sp_b + (size_t)lay * HID_,
            g_W1 + (size_t)lay * 192 * 64,
            g_b1 + (size_t)lay * 64,
            g_W2 + (size_t)lay * 64 * 3,
            g_b2 + (size_t)lay * 3,
            REC);
        k_recon<<<dim3(S_ / 256, B_), blk, 0, stream>>>(
            idx, sp_emb + (size_t)lay * NPSP_ * ED_, REC, h, sC);
    }

    k_proj<<<dim3(S_ / 256, B_), blk, 0, stream>>>(h, proj_W, proj_b, (float*)d_out);
}